// Round 10
// baseline (1272.351 us; speedup 1.0000x reference)
//
#include <hip/hip_runtime.h>

#define TT 2048
#define BB 128
#define II 32
#define HH 128
#define NW (TT / 8)

typedef float v2f __attribute__((ext_vector_type(2)));
typedef float v4f __attribute__((ext_vector_type(4)));
typedef unsigned int u32;
typedef __attribute__((address_space(3))) u32 lds_u32;
typedef const __attribute__((address_space(1))) u32 glb_u32;

// packed dual fp32 FMA (VOP3P)
__device__ __forceinline__ v2f pk_fma(v2f a, v2f b, v2f c) {
    v2f d;
    asm("v_pk_fma_f32 %0, %1, %2, %3" : "=v"(d) : "v"(a), "v"(b), "v"(c));
    return d;
}
// DPP ctrl: 0xB1 quad xor1, 0x4E quad xor2, 0x124 row_ror:4, 0x128 row_ror:8
template <int CTRL>
__device__ __forceinline__ float dpp_mov(float p) {
    return __int_as_float(__builtin_amdgcn_update_dpp(0, __float_as_int(p), CTRL, 0xF, 0xF, true));
}
template <int CTRL>
__device__ __forceinline__ float dpp_add(float p) { return p + dpp_mov<CTRL>(p); }
template <int CTRL>
__device__ __forceinline__ float pair_red(float x, float y, bool sel) {
    float keep = sel ? y : x;
    float give = sel ? x : y;
    return keep + dpp_mov<CTRL>(give);
}

// 4 waves x 64 lanes, TWO batch chains per block (64 blocks). Weights shared;
// each barrier interval advances BOTH chains one step (barrier/drain cost
// amortized 2x; the two dependency chains interleave as pure ILP).
// Per chain: R9 skeleton - 8 rows per 16-lane group, 4-deep pk_fma after
// precomputed wi*x+bias, DPP reduce (xor1,xor2 select; ror4,ror8 plain),
// tanh via exp2/rcp (weights prescaled 2*log2e), blend = 1 fma with
// hsum=al+(1-al)h maintained in slack. V into LDS vres, flushed at end.
__global__ __launch_bounds__(256)
void vrnn_kernel(const float* __restrict__ X, const float* __restrict__ W_in,
                 const float* __restrict__ W_hh, const float* __restrict__ rnn_bias,
                 const float* __restrict__ alpha, const float* __restrict__ value_W,
                 const float* __restrict__ value_bias, float* __restrict__ out)
{
    const int b0   = 2 * blockIdx.x;
    const int b1   = b0 + 1;
    const int tid  = threadIdx.x;
    const int wave = tid >> 6;        // 0..3
    const int lane = tid & 63;
    const int g    = lane >> 4;       // 0..3
    const int j    = lane & 15;       // 0..15
    const int base = 32 * wave + 8 * g;

    __shared__ __align__(16) float xw0[2][8][II];    // chain0 X windows
    __shared__ __align__(16) float xw1[2][8][II];    // chain1 X windows
    __shared__ __align__(16) float hbuf0[2][192];    // chain0 h (12-padded chunks)
    __shared__ __align__(16) float hbuf1[2][192];    // chain1 h
    __shared__ __align__(16) float vres[2][TT];      // V staging

    // ---- stage window 0 for both chains ----
    if (wave == 0) {
        const float* src = X + (size_t)(lane >> 3) * (BB * II) + b0 * II + (lane & 7) * 4;
        __builtin_amdgcn_global_load_lds((glb_u32*)src, (lds_u32*)(&xw0[0][0][0]), 16, 0, 0);
    }
    if (wave == 1) {
        const float* src = X + (size_t)(lane >> 3) * (BB * II) + b1 * II + (lane & 7) * 4;
        __builtin_amdgcn_global_load_lds((glb_u32*)src, (lds_u32*)(&xw1[0][0][0]), 16, 0, 0);
    }

    const float SC = 2.8853900817779268f;   // 2*log2(e) prescale (e = exp2(pre))

    // ---- shared per-lane constants (prescaled) ----
    v2f wh[8][4], wi8[8], binit[8];
#pragma unroll
    for (int r = 0; r < 8; ++r) {
        const float* wr = W_hh + (size_t)(base + r) * HH + 8 * j;
        v4f a0 = *(const v4f*)(wr);
        v4f a1 = *(const v4f*)(wr + 4);
        wh[r][0] = (v2f){a0.x * SC, a0.y * SC}; wh[r][1] = (v2f){a0.z * SC, a0.w * SC};
        wh[r][2] = (v2f){a1.x * SC, a1.y * SC}; wh[r][3] = (v2f){a1.z * SC, a1.w * SC};
        v2f wiv  = *(const v2f*)(W_in + (size_t)(base + r) * II + 2 * j);
        wi8[r]   = (v2f){wiv.x * SC, wiv.y * SC};
        binit[r] = (v2f){ (j == 0) ? rnn_bias[base + r] * SC : 0.0f, 0.0f };
    }
    v2f vwc[4];
#pragma unroll
    for (int i = 0; i < 4; ++i) vwc[i] = *(const v2f*)(value_W + 8 * j + 2 * i);
    const bool  b0s = (j & 1) != 0;
    const bool  b1s = (j & 2) != 0;
    const bool  selhi = ((j >> 2) & 1) != 0;
    const int   rown2 = base + (j & 3) + 4 * ((j >> 2) & 1);
    const float al_own = alpha[rown2];
    const float nal2   = -2.0f * al_own;
    const float oneml  = 1.0f - al_own;
    const float vb     = value_bias[0];
    const int   woff = 12 * (4 * wave + g) + (j & 3) + 4 * ((j >> 2) & 1);

    float hreg0 = 0.0f, hsum0 = al_own;
    float hreg1 = 0.0f, hsum1 = al_own;
    v2f   pinit0[8], pinit1[8];

    if (tid < 192) { hbuf0[1][tid] = 0.0f; hbuf1[1][tid] = 0.0f; }
    __syncthreads();

    float* outV = out;
    float* outH = out + (size_t)TT * BB;

#define STEP(S_)                                                               \
    {                                                                          \
        const int t   = 8 * w + (S_);                                          \
        const int par = (S_) & 1;                                              \
        /* both chains' h reads issued first */                                \
        const float* hbA = &hbuf0[par ^ 1][12 * j];                            \
        const v4f hA0 = *(const v4f*)(hbA);                                    \
        const v4f hA1 = *(const v4f*)(hbA + 4);                                \
        const float* hbB = &hbuf1[par ^ 1][12 * j];                            \
        const v4f hB0 = *(const v4f*)(hbB);                                    \
        const v4f hB1 = *(const v4f*)(hbB + 4);                                \
        v2f pinA[8], pinB[8];                                                  \
        if ((S_) == 0) {                                                       \
            const v2f xcA = *(const v2f*)(&xw0[w & 1][0][2 * j]);              \
            const v2f xcB = *(const v2f*)(&xw1[w & 1][0][2 * j]);              \
            _Pragma("unroll")                                                  \
            for (int r = 0; r < 8; ++r) {                                      \
                pinA[r] = pk_fma(wi8[r], xcA, binit[r]);                       \
                pinB[r] = pk_fma(wi8[r], xcB, binit[r]);                       \
            }                                                                  \
        } else {                                                               \
            _Pragma("unroll")                                                  \
            for (int r = 0; r < 8; ++r) { pinA[r] = pinit0[r]; pinB[r] = pinit1[r]; } \
        }                                                                      \
        v2f hpA[4] = { (v2f){hA0.x, hA0.y}, (v2f){hA0.z, hA0.w},               \
                       (v2f){hA1.x, hA1.y}, (v2f){hA1.z, hA1.w} };             \
        v2f hpB[4] = { (v2f){hB0.x, hB0.y}, (v2f){hB0.z, hB0.w},               \
                       (v2f){hB1.x, hB1.y}, (v2f){hB1.z, hB1.w} };             \
        float pA[8], pB[8];                                                    \
        _Pragma("unroll")                                                      \
        for (int r = 0; r < 8; ++r) {                                          \
            v2f a = pinA[r];                                                   \
            a = pk_fma(wh[r][0], hpA[0], a);                                   \
            a = pk_fma(wh[r][1], hpA[1], a);                                   \
            a = pk_fma(wh[r][2], hpA[2], a);                                   \
            a = pk_fma(wh[r][3], hpA[3], a);                                   \
            pA[r] = a.x + a.y;                                                 \
            v2f c = pinB[r];                                                   \
            c = pk_fma(wh[r][0], hpB[0], c);                                   \
            c = pk_fma(wh[r][1], hpB[1], c);                                   \
            c = pk_fma(wh[r][2], hpB[2], c);                                   \
            c = pk_fma(wh[r][3], hpB[3], c);                                   \
            pB[r] = c.x + c.y;                                                 \
        }                                                                      \
        float qA0 = pair_red<0xB1>(pA[0], pA[1], b0s);                         \
        float qA1 = pair_red<0xB1>(pA[2], pA[3], b0s);                         \
        float qA2 = pair_red<0xB1>(pA[4], pA[5], b0s);                         \
        float qA3 = pair_red<0xB1>(pA[6], pA[7], b0s);                         \
        float qB0 = pair_red<0xB1>(pB[0], pB[1], b0s);                         \
        float qB1 = pair_red<0xB1>(pB[2], pB[3], b0s);                         \
        float qB2 = pair_red<0xB1>(pB[4], pB[5], b0s);                         \
        float qB3 = pair_red<0xB1>(pB[6], pB[7], b0s);                         \
        float rA0 = pair_red<0x4E>(qA0, qA1, b1s);                             \
        float rA1 = pair_red<0x4E>(qA2, qA3, b1s);                             \
        float rB0 = pair_red<0x4E>(qB0, qB1, b1s);                             \
        float rB1 = pair_red<0x4E>(qB2, qB3, b1s);                             \
        rA0 = dpp_add<0x124>(rA0); rA1 = dpp_add<0x124>(rA1);                  \
        rB0 = dpp_add<0x124>(rB0); rB1 = dpp_add<0x124>(rB1);                  \
        rA0 = dpp_add<0x128>(rA0); rA1 = dpp_add<0x128>(rA1);                  \
        rB0 = dpp_add<0x128>(rB0); rB1 = dpp_add<0x128>(rB1);                  \
        const float preA = selhi ? rA1 : rA0;                                  \
        const float preB = selhi ? rB1 : rB0;                                  \
        const float eA  = __builtin_amdgcn_exp2f(preA);                        \
        const float eB  = __builtin_amdgcn_exp2f(preB);                        \
        const float rcA = __builtin_amdgcn_rcpf(eA + 1.0f);                    \
        const float rcB = __builtin_amdgcn_rcpf(eB + 1.0f);                    \
        hreg0 = fmaf(nal2, rcA, hsum0);                                        \
        hreg1 = fmaf(nal2, rcB, hsum1);                                        \
        hbuf0[par][woff] = hreg0;                                              \
        hbuf1[par][woff] = hreg1;                                              \
        /* ---- slack ---- */                                                  \
        hsum0 = fmaf(oneml, hreg0, al_own);                                    \
        hsum1 = fmaf(oneml, hreg1, al_own);                                    \
        if (((w | (S_)) != 0)) {                                               \
            if (wave == ((S_) & 3)) {                                          \
                v2f vt = vwc[0] * hpA[0];                                      \
                vt = pk_fma(vwc[1], hpA[1], vt);                               \
                vt = pk_fma(vwc[2], hpA[2], vt);                               \
                vt = pk_fma(vwc[3], hpA[3], vt);                               \
                float vs = vt.x + vt.y;                                        \
                vs = dpp_add<0xB1>(vs); vs = dpp_add<0x4E>(vs);                \
                vs = dpp_add<0x124>(vs); vs = dpp_add<0x128>(vs);              \
                if (lane == 0) vres[0][t - 1] = vb + vs;                       \
            }                                                                  \
            if (wave == (((S_) + 2) & 3)) {                                    \
                v2f vt = vwc[0] * hpB[0];                                      \
                vt = pk_fma(vwc[1], hpB[1], vt);                               \
                vt = pk_fma(vwc[2], hpB[2], vt);                               \
                vt = pk_fma(vwc[3], hpB[3], vt);                               \
                float vs = vt.x + vt.y;                                        \
                vs = dpp_add<0xB1>(vs); vs = dpp_add<0x4E>(vs);                \
                vs = dpp_add<0x124>(vs); vs = dpp_add<0x128>(vs);              \
                if (lane == 0) vres[1][t - 1] = vb + vs;                       \
            }                                                                  \
        }                                                                      \
        if ((S_) < 7) {                                                        \
            const v2f xnA = *(const v2f*)(&xw0[w & 1][(S_) + 1][2 * j]);       \
            const v2f xnB = *(const v2f*)(&xw1[w & 1][(S_) + 1][2 * j]);       \
            _Pragma("unroll")                                                  \
            for (int r = 0; r < 8; ++r) {                                      \
                pinit0[r] = pk_fma(wi8[r], xnA, binit[r]);                     \
                pinit1[r] = pk_fma(wi8[r], xnB, binit[r]);                     \
            }                                                                  \
        }                                                                      \
        if (wave <= 1 && (S_) == 7)                                            \
            asm volatile("s_waitcnt vmcnt(0)" ::: "memory");                   \
        asm volatile("s_waitcnt lgkmcnt(0)" ::: "memory");                     \
        __builtin_amdgcn_s_barrier();                                          \
    }

    for (int w = 0; w < NW; ++w) {
        if (w + 1 < NW) {
            if (wave == 0) {
                const float* src = X + (size_t)((w + 1) * 8 + (lane >> 3)) * (BB * II)
                                     + b0 * II + (lane & 7) * 4;
                __builtin_amdgcn_global_load_lds((glb_u32*)src,
                    (lds_u32*)(&xw0[(w + 1) & 1][0][0]), 16, 0, 0);
            }
            if (wave == 1) {
                const float* src = X + (size_t)((w + 1) * 8 + (lane >> 3)) * (BB * II)
                                     + b1 * II + (lane & 7) * 4;
                __builtin_amdgcn_global_load_lds((glb_u32*)src,
                    (lds_u32*)(&xw1[(w + 1) & 1][0][0]), 16, 0, 0);
            }
        }
        STEP(0) STEP(1) STEP(2) STEP(3) STEP(4) STEP(5) STEP(6) STEP(7)
    }
#undef STEP

    // ---- tail: V[T-1] for both chains (h parity 1), last_hidden, flush ----
    if (wave == 0 || wave == 1) {
        const float* hb = (wave == 0) ? &hbuf0[1][12 * j] : &hbuf1[1][12 * j];
        const v4f h0v = *(const v4f*)(hb);
        const v4f h1v = *(const v4f*)(hb + 4);
        v2f hp[4] = { (v2f){h0v.x, h0v.y}, (v2f){h0v.z, h0v.w},
                      (v2f){h1v.x, h1v.y}, (v2f){h1v.z, h1v.w} };
        v2f vt = vwc[0] * hp[0];
        vt = pk_fma(vwc[1], hp[1], vt);
        vt = pk_fma(vwc[2], hp[2], vt);
        vt = pk_fma(vwc[3], hp[3], vt);
        float vs = vt.x + vt.y;
        vs = dpp_add<0xB1>(vs); vs = dpp_add<0x4E>(vs);
        vs = dpp_add<0x124>(vs); vs = dpp_add<0x128>(vs);
        if (lane == 0) vres[wave][TT - 1] = vb + vs;
    }
    if (j < 8) {
        outH[(size_t)b0 * HH + base + j] = hreg0;
        outH[(size_t)b1 * HH + base + j] = hreg1;
    }
    __syncthreads();
#pragma unroll
    for (int i = 0; i < TT / 256; ++i) {
        outV[(size_t)(i * 256 + tid) * BB + b0] = vres[0][i * 256 + tid];
        outV[(size_t)(i * 256 + tid) * BB + b1] = vres[1][i * 256 + tid];
    }
}

extern "C" void kernel_launch(void* const* d_in, const int* in_sizes, int n_in,
                              void* d_out, int out_size, void* d_ws, size_t ws_size,
                              hipStream_t stream) {
    const float* X      = (const float*)d_in[0];
    const float* W_in   = (const float*)d_in[1];
    const float* W_hh   = (const float*)d_in[2];
    const float* rbias  = (const float*)d_in[3];
    const float* alpha  = (const float*)d_in[4];
    const float* vW     = (const float*)d_in[5];
    const float* vbias  = (const float*)d_in[6];
    float* out = (float*)d_out;

    vrnn_kernel<<<dim3(BB / 2), dim3(256), 0, stream>>>(X, W_in, W_hh, rbias, alpha, vW, vbias, out);
}